// Round 4
// baseline (694.724 us; speedup 1.0000x reference)
//
#include <hip/hip_runtime.h>

#define B     64
#define CIN   3
#define COUT  16
#define H     256
#define W     256
#define HW    (H*W)
#define CHW   (CIN*H*W)
#define HO    255            // conv out spatial
#define WO    255
#define HF    254            // window out spatial
#define WF    254
#define NPIXF 4161600.0f     // B*HO*WO
#define BN_EPS 1e-5f
#define C2TANH 2.8853900817779268f   // 2*log2(e)

#define SEGS  32                     // 8-px segments per conv row
#define NITEM (B * HO * SEGS)        // 522,240
#define STB   1020                   // k_stats blocks (4 blocks/CU)
#define SITER 2                      // 1020*256*2 == NITEM

#define RB    15                     // output rows per fused block (16 s-rows)
#define RBLKS 17                     // 17*15 = 255 >= 254
#define LSTR  260                    // LDS s-tile row stride (bank-friendly)

typedef float f2 __attribute__((ext_vector_type(2)));
__device__ __forceinline__ float4 ld4(const float* p) { return *(const float4*)p; }
__device__ __forceinline__ f2 pkfma(f2 a, f2 b, f2 c) { return __builtin_elementwise_fma(a, b, c); }
__device__ __forceinline__ f2 spl(float v) { return (f2){v, v}; }

// ---- kernel 1: per-channel sum/sumsq of conv+bias (channel stats, 4-px halves) ----
__global__ __launch_bounds__(256, 4) void k_stats(const float* __restrict__ x,
                                                  const float* __restrict__ w,
                                                  const float* __restrict__ bias,
                                                  float* __restrict__ acc) {
    __shared__ float wpk[COUT * 16];
    int tid = threadIdx.x;
    {
        int c = tid >> 4, k = tid & 15;
        float v = 0.f;
        if (k < 12)       v = w[c * 12 + k];
        else if (k == 12) v = bias[c];
        wpk[tid] = v;
    }
    __syncthreads();

    float s[COUT], q[COUT];
#pragma unroll
    for (int c = 0; c < COUT; c++) { s[c] = 0.f; q[c] = 0.f; }

    int gtid = blockIdx.x * 256 + tid;
#pragma unroll 1
    for (int it = 0; it < SITER; it++) {
        int item = gtid + it * (STB * 256);
        int jseg = item & 31;
        int row  = item >> 5;              // b*HO + i
        int bb   = row / HO;
        int i    = row - bb * HO;
        const float* xp = x + (size_t)bb * CHW + i * W + (jseg << 3);
        bool tail = (jseg == 31);

#pragma unroll 1
        for (int h = 0; h < 2; h++) {      // two 4-px halves (keeps VGPR low)
            const float* ph = xp + (h << 2);
            bool th = tail && (h == 1);
            int  eo = th ? 3 : 4;          // clamp 5th col for the very last px
            float xr[2][CIN][5];
#pragma unroll
            for (int ic = 0; ic < CIN; ic++) {
                const float* p0 = ph + ic * HW;
                const float* p1 = p0 + W;
                float4 a = ld4(p0);
                xr[0][ic][0] = a.x; xr[0][ic][1] = a.y; xr[0][ic][2] = a.z; xr[0][ic][3] = a.w;
                xr[0][ic][4] = p0[eo];
                float4 b4 = ld4(p1);
                xr[1][ic][0] = b4.x; xr[1][ic][1] = b4.y; xr[1][ic][2] = b4.z; xr[1][ic][3] = b4.w;
                xr[1][ic][4] = p1[eo];
            }
            float m3 = th ? 0.f : 1.f;     // mask invalid col-255 pixel
#pragma unroll
            for (int c = 0; c < COUT; c++) {
                const float4* wv = (const float4*)(wpk + (c << 4));
                float4 wa = wv[0], wb = wv[1], wc4 = wv[2], wd = wv[3];
#pragma unroll
                for (int u = 0; u < 4; u++) {
                    float f = wd.x;
                    f = fmaf(wa.x,  xr[0][0][u], f); f = fmaf(wa.y,  xr[0][0][u+1], f);
                    f = fmaf(wa.z,  xr[1][0][u], f); f = fmaf(wa.w,  xr[1][0][u+1], f);
                    f = fmaf(wb.x,  xr[0][1][u], f); f = fmaf(wb.y,  xr[0][1][u+1], f);
                    f = fmaf(wb.z,  xr[1][1][u], f); f = fmaf(wb.w,  xr[1][1][u+1], f);
                    f = fmaf(wc4.x, xr[0][2][u], f); f = fmaf(wc4.y, xr[0][2][u+1], f);
                    f = fmaf(wc4.z, xr[1][2][u], f); f = fmaf(wc4.w, xr[1][2][u+1], f);
                    if (u == 3) f *= m3;
                    s[c] += f;
                    q[c] = fmaf(f, f, q[c]);
                }
            }
        }
    }

    // wave64 butterfly, cross-wave LDS, 32 atomics per block
#pragma unroll
    for (int c = 0; c < COUT; c++) {
        for (int off = 32; off; off >>= 1) {
            s[c] += __shfl_down(s[c], off, 64);
            q[c] += __shfl_down(q[c], off, 64);
        }
    }
    __shared__ float red[4][2 * COUT];
    int wave = tid >> 6, lane = tid & 63;
    if (lane == 0) {
#pragma unroll
        for (int c = 0; c < COUT; c++) {
            red[wave][c] = s[c];
            red[wave][COUT + c] = q[c];
        }
    }
    __syncthreads();
    if (tid < 2 * COUT) {
        float v = red[0][tid] + red[1][tid] + red[2][tid] + red[3][tid];
        atomicAdd(&acc[tid], v);
    }
}

// ---- kernel 2 (fused): BN finalize + s=sum_c tanh(relu(bn(conv))) tile + 2x2 window mean ----
__global__ __launch_bounds__(256) void k_csum(const float* __restrict__ x,
                                              const float* __restrict__ w,
                                              const float* __restrict__ bias,
                                              const float* __restrict__ gamma,
                                              const float* __restrict__ beta,
                                              const float* __restrict__ acc,
                                              float* __restrict__ out) {
    __shared__ float wpk[COUT * 16];
    __shared__ float sld[16 * LSTR];
    int tid = threadIdx.x;
    {   // [0..11]=w, [12]=bias, [13]=scale*C2, [14]=shift*C2 (BN finalize fused here)
        int c = tid >> 4, k = tid & 15;
        float v = 0.f;
        if (k < 12)       v = w[c * 12 + k];
        else if (k == 12) v = bias[c];
        else if (k < 15) {
            float sv = acc[c], qv = acc[COUT + c];
            float mu  = sv * (1.f / NPIXF);
            float var = qv * (1.f / NPIXF) - mu * mu;
            float sc  = gamma[c] * rsqrtf(var + BN_EPS);
            v = (k == 13) ? sc * C2TANH : (beta[c] - mu * sc) * C2TANH;
        }
        wpk[tid] = v;
    }
    int blk = blockIdx.x;
    int bb = blk / RBLKS, rblk = blk - bb * RBLKS;
    int rbase = rblk * RB;
    __syncthreads();

    // phase 1: 16 s-rows x 32 segments; thread handles (sr, sr+8) x jseg; f2 = pixel pair
    int jseg = tid & 31, j0 = jseg << 3;
#pragma unroll 1
    for (int rep = 0; rep < 2; rep++) {
        int sr = (tid >> 5) + (rep << 3);
        int si = rbase + sr;
        if (si < HO) {
            const float* xp = x + (size_t)bb * CHW + si * W + j0;
            bool tail = (jseg == 31);
#pragma unroll 1
            for (int h = 0; h < 2; h++) {
                const float* ph = xp + (h << 2);
                bool th = tail && (h == 1);
                int  eo = th ? 3 : 4;
                f2 pp[2][CIN][2], ss[2][CIN][2];
#pragma unroll
                for (int ic = 0; ic < CIN; ic++) {
#pragma unroll
                    for (int r = 0; r < 2; r++) {
                        const float* p = ph + ic * HW + r * W;
                        float4 a = ld4(p);
                        float  e = p[eo];
                        pp[r][ic][0] = (f2){a.x, a.y}; pp[r][ic][1] = (f2){a.z, a.w};
                        ss[r][ic][0] = (f2){a.y, a.z}; ss[r][ic][1] = (f2){a.w, e};
                    }
                }
                f2 r0 = spl(0.f), r1 = spl(0.f);
#pragma unroll
                for (int c = 0; c < COUT; c++) {
                    const float4* wv = (const float4*)(wpk + (c << 4));
                    float4 wa = wv[0], wb = wv[1], wc4 = wv[2], wd = wv[3];
                    f2 f0 = spl(wd.x), f1 = spl(wd.x);
                    f0 = pkfma(spl(wa.x),  pp[0][0][0], f0); f1 = pkfma(spl(wa.x),  pp[0][0][1], f1);
                    f0 = pkfma(spl(wa.y),  ss[0][0][0], f0); f1 = pkfma(spl(wa.y),  ss[0][0][1], f1);
                    f0 = pkfma(spl(wa.z),  pp[1][0][0], f0); f1 = pkfma(spl(wa.z),  pp[1][0][1], f1);
                    f0 = pkfma(spl(wa.w),  ss[1][0][0], f0); f1 = pkfma(spl(wa.w),  ss[1][0][1], f1);
                    f0 = pkfma(spl(wb.x),  pp[0][1][0], f0); f1 = pkfma(spl(wb.x),  pp[0][1][1], f1);
                    f0 = pkfma(spl(wb.y),  ss[0][1][0], f0); f1 = pkfma(spl(wb.y),  ss[0][1][1], f1);
                    f0 = pkfma(spl(wb.z),  pp[1][1][0], f0); f1 = pkfma(spl(wb.z),  pp[1][1][1], f1);
                    f0 = pkfma(spl(wb.w),  ss[1][1][0], f0); f1 = pkfma(spl(wb.w),  ss[1][1][1], f1);
                    f0 = pkfma(spl(wc4.x), pp[0][2][0], f0); f1 = pkfma(spl(wc4.x), pp[0][2][1], f1);
                    f0 = pkfma(spl(wc4.y), ss[0][2][0], f0); f1 = pkfma(spl(wc4.y), ss[0][2][1], f1);
                    f0 = pkfma(spl(wc4.z), pp[1][2][0], f0); f1 = pkfma(spl(wc4.z), pp[1][2][1], f1);
                    f0 = pkfma(spl(wc4.w), ss[1][2][0], f0); f1 = pkfma(spl(wc4.w), ss[1][2][1], f1);
                    f2 a0 = pkfma(spl(wd.y), f0, spl(wd.z));   // (scale*f+shift)*2log2e
                    f2 a1 = pkfma(spl(wd.y), f1, spl(wd.z));
                    a0 = __builtin_elementwise_max(a0, spl(0.f));
                    a1 = __builtin_elementwise_max(a1, spl(0.f));
                    f2 E0, E1;
                    E0.x = __builtin_amdgcn_exp2f(a0.x); E0.y = __builtin_amdgcn_exp2f(a0.y);
                    E1.x = __builtin_amdgcn_exp2f(a1.x); E1.y = __builtin_amdgcn_exp2f(a1.y);
                    E0 += spl(1.f); E1 += spl(1.f);
                    f2 rc0, rc1;
                    rc0.x = __builtin_amdgcn_rcpf(E0.x); rc0.y = __builtin_amdgcn_rcpf(E0.y);
                    rc1.x = __builtin_amdgcn_rcpf(E1.x); rc1.y = __builtin_amdgcn_rcpf(E1.y);
                    r0 += rc0; r1 += rc1;
                }
                // s = COUT - 2*sum(r)  (tanh = 1 - 2/(e^{2a}+1), +1 folded out of loop)
                f2 s0 = pkfma(spl(-2.f), r0, spl((float)COUT));
                f2 s1 = pkfma(spl(-2.f), r1, spl((float)COUT));
                float* sp = &sld[sr * LSTR + j0 + (h << 2)];
                *(float4*)sp = make_float4(s0.x, s0.y, s1.x, s1.y);
            }
        }
    }
    __syncthreads();

    // phase 2: 2x2 window means over the LDS s-tile
    int orl = tid >> 5, oc0 = tid & 31;
#pragma unroll 1
    for (int rep = 0; rep < 2; rep++) {
        int o = orl + (rep << 3);
        int orow = rbase + o;
        if (o < RB && orow < HF) {
            const float* s0 = &sld[o * LSTR];
            const float* s1 = s0 + LSTR;
            float* op = out + ((size_t)bb * HF + orow) * WF;
#pragma unroll
            for (int u = 0; u < 8; u++) {
                int c = oc0 + (u << 5);
                if (c < WF) {
                    op[c] = (s0[c] + s0[c+1] + s1[c] + s1[c+1]) * (1.f / (COUT * 4));
                }
            }
        }
    }
}

extern "C" void kernel_launch(void* const* d_in, const int* in_sizes, int n_in,
                              void* d_out, int out_size, void* d_ws, size_t ws_size,
                              hipStream_t stream) {
    const float* x     = (const float*)d_in[0];
    const float* w     = (const float*)d_in[1];
    const float* bias  = (const float*)d_in[2];
    const float* gamma = (const float*)d_in[3];
    const float* beta  = (const float*)d_in[4];
    float* out = (float*)d_out;

    float* acc = (float*)d_ws;      // 32 floats: s[16], q[16]

    hipMemsetAsync(d_ws, 0, 128, stream);
    k_stats<<<STB, 256, 0, stream>>>(x, w, bias, acc);
    k_csum<<<B * RBLKS, 256, 0, stream>>>(x, w, bias, gamma, beta, acc, out);
}

// Round 5
// 182.115 us; speedup vs baseline: 3.8148x; 3.8148x over previous
//
#include <hip/hip_runtime.h>

#define B     64
#define CIN   3
#define COUT  16
#define H     256
#define W     256
#define HW    (H*W)
#define CHW   (CIN*H*W)
#define HO    255            // conv out spatial
#define WO    255
#define HF    254            // window out spatial
#define WF    254
#define NPIXF 4161600.0f     // B*HO*WO
#define BN_EPS 1e-5f
#define C2TANH 2.8853900817779268f   // 2*log2(e)

#define SEGS  32                     // 8-px segments per conv row
#define NITEM (B * HO * SEGS)        // 522,240 = 2040 * 256
#define STB   (NITEM / 256)          // 2040 blocks, one segment per thread

#define RB    7                      // output rows per fused block (8 s-rows)
#define RBLKS 37                     // ceil(HF/RB)
#define LSTR  260                    // LDS s-tile row stride

__device__ __forceinline__ float4 ld4(const float* p) { return *(const float4*)p; }

// Load the 2 x 9 x 3ch input patch for an 8-pixel segment. off8 clamps the
// 9th column in-bounds for the tail segment (its value is masked/unused).
__device__ __forceinline__ void load_patch(const float* xp, int off8,
                                           float x0[CIN][9], float x1[CIN][9]) {
#pragma unroll
    for (int ic = 0; ic < CIN; ic++) {
        const float* p0 = xp + ic * HW;
        const float* p1 = p0 + W;
        float4 a = ld4(p0), b = ld4(p0 + 4);
        x0[ic][0] = a.x; x0[ic][1] = a.y; x0[ic][2] = a.z; x0[ic][3] = a.w;
        x0[ic][4] = b.x; x0[ic][5] = b.y; x0[ic][6] = b.z; x0[ic][7] = b.w;
        x0[ic][8] = p0[off8];
        float4 c4 = ld4(p1), d = ld4(p1 + 4);
        x1[ic][0] = c4.x; x1[ic][1] = c4.y; x1[ic][2] = c4.z; x1[ic][3] = c4.w;
        x1[ic][4] = d.x;  x1[ic][5] = d.y;  x1[ic][6] = d.z;  x1[ic][7] = d.w;
        x1[ic][8] = p1[off8];
    }
}

#define CONV_F(u)                                                  \
    float f = wd.x;                                                \
    f = fmaf(wa.x, x0[0][u], f); f = fmaf(wa.y, x0[0][(u)+1], f);  \
    f = fmaf(wa.z, x1[0][u], f); f = fmaf(wa.w, x1[0][(u)+1], f);  \
    f = fmaf(wb.x, x0[1][u], f); f = fmaf(wb.y, x0[1][(u)+1], f);  \
    f = fmaf(wb.z, x1[1][u], f); f = fmaf(wb.w, x1[1][(u)+1], f);  \
    f = fmaf(wc4.x, x0[2][u], f); f = fmaf(wc4.y, x0[2][(u)+1], f);\
    f = fmaf(wc4.z, x1[2][u], f); f = fmaf(wc4.w, x1[2][(u)+1], f);

// ---- kernel 1: per-channel sum/sumsq of conv+bias; one 8-px segment per thread ----
__global__ __launch_bounds__(256) void k_stats(const float* __restrict__ x,
                                               const float* __restrict__ w,
                                               const float* __restrict__ bias,
                                               float* __restrict__ acc) {
    __shared__ float wpk[COUT * 16];
    int tid = threadIdx.x;
    {   // packed per-channel params: [0..11]=w, [12]=bias
        int c = tid >> 4, k = tid & 15;
        float v = 0.f;
        if (k < 12)       v = w[c * 12 + k];
        else if (k == 12) v = bias[c];
        wpk[tid] = v;
    }
    __syncthreads();

    int item = blockIdx.x * 256 + tid;
    int jseg = item & (SEGS - 1);
    int row  = item >> 5;                 // b*HO + i
    int bb   = row / HO;
    int i    = row - bb * HO;
    const float* xp = x + (size_t)bb * CHW + i * W + (jseg << 3);
    bool tail = (jseg == SEGS - 1);
    int  off8 = tail ? 7 : 8;
    float m7  = tail ? 0.f : 1.f;         // mask invalid col-255 pixel

    float x0[CIN][9], x1[CIN][9];
    load_patch(xp, off8, x0, x1);

    float s[COUT], q[COUT];
#pragma unroll
    for (int c = 0; c < COUT; c++) {
        const float4* wv = (const float4*)(wpk + (c << 4));
        float4 wa = wv[0], wb = wv[1], wc4 = wv[2], wd = wv[3];
        float sc_ = 0.f, qc_ = 0.f;
#pragma unroll
        for (int u = 0; u < 8; u++) {
            CONV_F(u)
            if (u == 7) f *= m7;
            sc_ += f;
            qc_ = fmaf(f, f, qc_);
        }
        s[c] = sc_;
        q[c] = qc_;
    }

    // wave64 butterfly, cross-wave LDS, 32 atomics per block
#pragma unroll
    for (int c = 0; c < COUT; c++) {
        for (int off = 32; off; off >>= 1) {
            s[c] += __shfl_down(s[c], off, 64);
            q[c] += __shfl_down(q[c], off, 64);
        }
    }
    __shared__ float red[4][2 * COUT];
    int wave = tid >> 6, lane = tid & 63;
    if (lane == 0) {
#pragma unroll
        for (int c = 0; c < COUT; c++) {
            red[wave][c] = s[c];
            red[wave][COUT + c] = q[c];
        }
    }
    __syncthreads();
    if (tid < 2 * COUT) {
        float v = red[0][tid] + red[1][tid] + red[2][tid] + red[3][tid];
        atomicAdd(&acc[tid], v);
    }
}

// ---- kernel 2 (fused): BN finalize + s=sum_c tanh(relu(bn(conv))) tile + 2x2 window mean ----
__global__ __launch_bounds__(256) void k_csum(const float* __restrict__ x,
                                              const float* __restrict__ w,
                                              const float* __restrict__ bias,
                                              const float* __restrict__ gamma,
                                              const float* __restrict__ beta,
                                              const float* __restrict__ acc,
                                              float* __restrict__ out) {
    __shared__ float wpk[COUT * 16];
    __shared__ float sld[(RB + 1) * LSTR];
    int tid = threadIdx.x;
    {   // [0..11]=w, [12]=bias, [13]=scale*C2, [14]=shift*C2 (BN finalize fused)
        int c = tid >> 4, k = tid & 15;
        float v = 0.f;
        if (k < 12)       v = w[c * 12 + k];
        else if (k == 12) v = bias[c];
        else if (k < 15) {
            float sv = acc[c], qv = acc[COUT + c];
            float mu  = sv * (1.f / NPIXF);
            float var = qv * (1.f / NPIXF) - mu * mu;
            float sc  = gamma[c] * rsqrtf(var + BN_EPS);
            v = (k == 13) ? sc * C2TANH : (beta[c] - mu * sc) * C2TANH;
        }
        wpk[tid] = v;
    }
    int blk   = blockIdx.x;
    int bb    = blk / RBLKS;
    int rblk  = blk - bb * RBLKS;
    int rbase = rblk * RB;
    __syncthreads();

    // phase 1: one 8-pixel s-segment per thread (8 rows x 32 segs = 256 tasks)
    int sr = tid >> 5;               // 0..7
    int si = rbase + sr;
    int jseg = tid & 31;
    int j0 = jseg << 3;
    if (si < HO) {
        const float* xp = x + (size_t)bb * CHW + si * W + j0;
        int off8 = (jseg == 31) ? 7 : 8;
        float x0[CIN][9], x1[CIN][9];
        load_patch(xp, off8, x0, x1);

        float sum[8];
#pragma unroll
        for (int u = 0; u < 8; u++) sum[u] = 0.f;

#pragma unroll
        for (int c = 0; c < COUT; c++) {
            const float4* wv4 = (const float4*)(wpk + (c << 4));
            float4 wa = wv4[0], wb = wv4[1], wc4 = wv4[2], wd = wv4[3];
#pragma unroll
            for (int u = 0; u < 8; u++) {
                CONV_F(u)
                float a2 = fmaf(wd.y, f, wd.z);            // 2log2e*(scale*f+shift)
                a2 = fmaxf(a2, 0.f);                       // relu (scaled)
                float E = __builtin_amdgcn_exp2f(a2);      // e^{2a}
                float r = __builtin_amdgcn_rcpf(E + 1.f);
                sum[u] += r;                               // sum of 1/(e^{2a}+1)
            }
        }
        // s = COUT - 2*sum(r)   (tanh = 1 - 2/(e^{2a}+1))
        float* sp = &sld[sr * LSTR + j0];
        *(float4*)sp       = make_float4(fmaf(-2.f, sum[0], (float)COUT),
                                         fmaf(-2.f, sum[1], (float)COUT),
                                         fmaf(-2.f, sum[2], (float)COUT),
                                         fmaf(-2.f, sum[3], (float)COUT));
        *(float4*)(sp + 4) = make_float4(fmaf(-2.f, sum[4], (float)COUT),
                                         fmaf(-2.f, sum[5], (float)COUT),
                                         fmaf(-2.f, sum[6], (float)COUT),
                                         fmaf(-2.f, sum[7], (float)COUT));
    }
    __syncthreads();

    // phase 2: 2x2 window means; thread -> (row tid>>5, cols (tid&31)+32u) coalesced
    int orl = tid >> 5;              // 0..7, valid rows 0..RB-1
    int orow = rbase + orl;
    if (orl < RB && orow < HF) {
        const float* s0 = &sld[orl * LSTR];
        const float* s1 = s0 + LSTR;
        float* op = out + ((size_t)bb * HF + orow) * WF;
        int oc0 = tid & 31;
#pragma unroll
        for (int u = 0; u < 8; u++) {
            int c = oc0 + (u << 5);
            if (c < WF) {
                op[c] = (s0[c] + s0[c+1] + s1[c] + s1[c+1]) * (1.f / (COUT * 4));
            }
        }
    }
}

extern "C" void kernel_launch(void* const* d_in, const int* in_sizes, int n_in,
                              void* d_out, int out_size, void* d_ws, size_t ws_size,
                              hipStream_t stream) {
    const float* x     = (const float*)d_in[0];
    const float* w     = (const float*)d_in[1];
    const float* bias  = (const float*)d_in[2];
    const float* gamma = (const float*)d_in[3];
    const float* beta  = (const float*)d_in[4];
    float* out = (float*)d_out;

    float* acc = (float*)d_ws;      // 32 floats: s[16], q[16]

    hipMemsetAsync(d_ws, 0, 128, stream);
    k_stats<<<STB, 256, 0, stream>>>(x, w, bias, acc);
    k_csum<<<B * RBLKS, 256, 0, stream>>>(x, w, bias, gamma, beta, acc, out);
}

// Round 6
// 154.838 us; speedup vs baseline: 4.4868x; 1.1762x over previous
//
#include <hip/hip_runtime.h>

#define B     64
#define CIN   3
#define COUT  16
#define H     256
#define W     256
#define HW    (H*W)
#define CHW   (CIN*H*W)
#define HO    255            // conv out spatial
#define WO    255
#define HF    254            // window out spatial
#define WF    254
#define NPIXF 4161600.0f     // B*HO*WO
#define BN_EPS 1e-5f
#define C2TANH 2.8853900817779268f   // 2*log2(e)

#define SEGS  32                     // 8-px segments per conv row
#define NITEM (B * HO * SEGS)        // 522,240 = 2040 * 256
#define STB   (NITEM / 256)          // 2040 blocks, one segment per thread
#define RCHUNK (STB / 8)             // 255 partial entries per reduce-thread

#define RB    7                      // output rows per fused block (8 s-rows)
#define RBLKS 37                     // ceil(HF/RB)
#define LSTR  260                    // LDS s-tile row stride

__device__ __forceinline__ float4 ld4(const float* p) { return *(const float4*)p; }

// Load the 2 x 9 x 3ch input patch for an 8-pixel segment. off8 clamps the
// 9th column in-bounds for the tail segment (its value is masked/unused).
__device__ __forceinline__ void load_patch(const float* xp, int off8,
                                           float x0[CIN][9], float x1[CIN][9]) {
#pragma unroll
    for (int ic = 0; ic < CIN; ic++) {
        const float* p0 = xp + ic * HW;
        const float* p1 = p0 + W;
        float4 a = ld4(p0), b = ld4(p0 + 4);
        x0[ic][0] = a.x; x0[ic][1] = a.y; x0[ic][2] = a.z; x0[ic][3] = a.w;
        x0[ic][4] = b.x; x0[ic][5] = b.y; x0[ic][6] = b.z; x0[ic][7] = b.w;
        x0[ic][8] = p0[off8];
        float4 c4 = ld4(p1), d = ld4(p1 + 4);
        x1[ic][0] = c4.x; x1[ic][1] = c4.y; x1[ic][2] = c4.z; x1[ic][3] = c4.w;
        x1[ic][4] = d.x;  x1[ic][5] = d.y;  x1[ic][6] = d.z;  x1[ic][7] = d.w;
        x1[ic][8] = p1[off8];
    }
}

#define CONV_F(u)                                                  \
    float f = wd.x;                                                \
    f = fmaf(wa.x, x0[0][u], f); f = fmaf(wa.y, x0[0][(u)+1], f);  \
    f = fmaf(wa.z, x1[0][u], f); f = fmaf(wa.w, x1[0][(u)+1], f);  \
    f = fmaf(wb.x, x0[1][u], f); f = fmaf(wb.y, x0[1][(u)+1], f);  \
    f = fmaf(wb.z, x1[1][u], f); f = fmaf(wb.w, x1[1][(u)+1], f);  \
    f = fmaf(wc4.x, x0[2][u], f); f = fmaf(wc4.y, x0[2][(u)+1], f);\
    f = fmaf(wc4.z, x1[2][u], f); f = fmaf(wc4.w, x1[2][(u)+1], f);

// ---- kernel 1: per-channel sum/sumsq of conv+bias; one 8-px segment per thread.
//      Reduction: LDS transpose (no shuffles), per-block partials (no atomics).
__global__ __launch_bounds__(256) void k_stats(const float* __restrict__ x,
                                               const float* __restrict__ w,
                                               const float* __restrict__ bias,
                                               float* __restrict__ part) {
    __shared__ float wpk[COUT * 16];
    __shared__ float tr[256 * 33];   // [thread][c] stride 33 -> bank (tid+c)%32
    __shared__ float red2[8 * 33];
    int tid = threadIdx.x;
    {   // packed per-channel params: [0..11]=w, [12]=bias
        int c = tid >> 4, k = tid & 15;
        float v = 0.f;
        if (k < 12)       v = w[c * 12 + k];
        else if (k == 12) v = bias[c];
        wpk[tid] = v;
    }
    __syncthreads();

    int item = blockIdx.x * 256 + tid;
    int jseg = item & (SEGS - 1);
    int row  = item >> 5;                 // b*HO + i
    int bb   = row / HO;
    int i    = row - bb * HO;
    const float* xp = x + (size_t)bb * CHW + i * W + (jseg << 3);
    bool tail = (jseg == SEGS - 1);
    int  off8 = tail ? 7 : 8;
    float m7  = tail ? 0.f : 1.f;         // mask invalid col-255 pixel

    float x0[CIN][9], x1[CIN][9];
    load_patch(xp, off8, x0, x1);

#pragma unroll
    for (int c = 0; c < COUT; c++) {
        const float4* wv = (const float4*)(wpk + (c << 4));
        float4 wa = wv[0], wb = wv[1], wc4 = wv[2], wd = wv[3];
        float sc_ = 0.f, qc_ = 0.f;
#pragma unroll
        for (int u = 0; u < 8; u++) {
            CONV_F(u)
            if (u == 7) f *= m7;
            sc_ += f;
            qc_ = fmaf(f, f, qc_);
        }
        tr[tid * 33 + c]        = sc_;   // conflict-free: bank (tid+c)%32
        tr[tid * 33 + COUT + c] = qc_;
    }
    __syncthreads();

    // column-chunk sums: thread (col=tid&31, chunk=tid>>5) sums 32 rows
    {
        int col = tid & 31, chunk = tid >> 5;
        int r0 = chunk << 5;
        float a0 = 0.f, a1 = 0.f, a2 = 0.f, a3 = 0.f;
#pragma unroll
        for (int k = 0; k < 32; k += 4) {
            a0 += tr[(r0 + k)     * 33 + col];
            a1 += tr[(r0 + k + 1) * 33 + col];
            a2 += tr[(r0 + k + 2) * 33 + col];
            a3 += tr[(r0 + k + 3) * 33 + col];
        }
        red2[chunk * 33 + col] = (a0 + a1) + (a2 + a3);
    }
    __syncthreads();
    if (tid < 32) {
        float s = 0.f;
#pragma unroll
        for (int k = 0; k < 8; k++) s += red2[k * 33 + tid];
        part[blockIdx.x * 32 + tid] = s;
    }
}

// ---- kernel 1b: fold 2040 x 32 partials -> acc[32] (one block, coalesced) ----
__global__ __launch_bounds__(256) void k_reduce(const float* __restrict__ part,
                                                float* __restrict__ acc) {
    __shared__ float red2[8 * 33];
    int tid = threadIdx.x;
    int col = tid & 31, chunk = tid >> 5;
    int base = chunk * RCHUNK;
    float a0 = 0.f, a1 = 0.f, a2 = 0.f, a3 = 0.f;
    int k = 0;
    for (; k + 3 < RCHUNK; k += 4) {
        a0 += part[(base + k)     * 32 + col];
        a1 += part[(base + k + 1) * 32 + col];
        a2 += part[(base + k + 2) * 32 + col];
        a3 += part[(base + k + 3) * 32 + col];
    }
    for (; k < RCHUNK; k++) a0 += part[(base + k) * 32 + col];
    red2[chunk * 33 + col] = (a0 + a1) + (a2 + a3);
    __syncthreads();
    if (tid < 32) {
        float s = 0.f;
#pragma unroll
        for (int j = 0; j < 8; j++) s += red2[j * 33 + tid];
        acc[tid] = s;
    }
}

// ---- kernel 2 (fused): BN finalize + s=sum_c tanh(relu(bn(conv))) tile + 2x2 window mean ----
__global__ __launch_bounds__(256) void k_csum(const float* __restrict__ x,
                                              const float* __restrict__ w,
                                              const float* __restrict__ bias,
                                              const float* __restrict__ gamma,
                                              const float* __restrict__ beta,
                                              const float* __restrict__ acc,
                                              float* __restrict__ out) {
    __shared__ float wpk[COUT * 16];
    __shared__ float sld[(RB + 1) * LSTR];
    int tid = threadIdx.x;
    {   // [0..11]=w, [12]=bias, [13]=scale*C2, [14]=shift*C2 (BN finalize fused)
        int c = tid >> 4, k = tid & 15;
        float v = 0.f;
        if (k < 12)       v = w[c * 12 + k];
        else if (k == 12) v = bias[c];
        else if (k < 15) {
            float sv = acc[c], qv = acc[COUT + c];
            float mu  = sv * (1.f / NPIXF);
            float var = qv * (1.f / NPIXF) - mu * mu;
            float sc  = gamma[c] * rsqrtf(var + BN_EPS);
            v = (k == 13) ? sc * C2TANH : (beta[c] - mu * sc) * C2TANH;
        }
        wpk[tid] = v;
    }
    int blk   = blockIdx.x;
    int bb    = blk / RBLKS;
    int rblk  = blk - bb * RBLKS;
    int rbase = rblk * RB;
    __syncthreads();

    // phase 1: one 8-pixel s-segment per thread (8 rows x 32 segs = 256 tasks)
    int sr = tid >> 5;               // 0..7
    int si = rbase + sr;
    int jseg = tid & 31;
    int j0 = jseg << 3;
    if (si < HO) {
        const float* xp = x + (size_t)bb * CHW + si * W + j0;
        int off8 = (jseg == 31) ? 7 : 8;
        float x0[CIN][9], x1[CIN][9];
        load_patch(xp, off8, x0, x1);

        float sum[8];
#pragma unroll
        for (int u = 0; u < 8; u++) sum[u] = 0.f;

#pragma unroll
        for (int c = 0; c < COUT; c++) {
            const float4* wv4 = (const float4*)(wpk + (c << 4));
            float4 wa = wv4[0], wb = wv4[1], wc4 = wv4[2], wd = wv4[3];
#pragma unroll
            for (int u = 0; u < 8; u++) {
                CONV_F(u)
                float a2 = fmaf(wd.y, f, wd.z);            // 2log2e*(scale*f+shift)
                a2 = fmaxf(a2, 0.f);                       // relu (scaled)
                float E = __builtin_amdgcn_exp2f(a2);      // e^{2a}
                float r = __builtin_amdgcn_rcpf(E + 1.f);
                sum[u] += r;                               // sum of 1/(e^{2a}+1)
            }
        }
        // s = COUT - 2*sum(r)   (tanh = 1 - 2/(e^{2a}+1))
        float* sp = &sld[sr * LSTR + j0];
        *(float4*)sp       = make_float4(fmaf(-2.f, sum[0], (float)COUT),
                                         fmaf(-2.f, sum[1], (float)COUT),
                                         fmaf(-2.f, sum[2], (float)COUT),
                                         fmaf(-2.f, sum[3], (float)COUT));
        *(float4*)(sp + 4) = make_float4(fmaf(-2.f, sum[4], (float)COUT),
                                         fmaf(-2.f, sum[5], (float)COUT),
                                         fmaf(-2.f, sum[6], (float)COUT),
                                         fmaf(-2.f, sum[7], (float)COUT));
    }
    __syncthreads();

    // phase 2: 2x2 window means; thread -> (row tid>>5, cols (tid&31)+32u) coalesced
    int orl = tid >> 5;              // 0..7, valid rows 0..RB-1
    int orow = rbase + orl;
    if (orl < RB && orow < HF) {
        const float* s0 = &sld[orl * LSTR];
        const float* s1 = s0 + LSTR;
        float* op = out + ((size_t)bb * HF + orow) * WF;
        int oc0 = tid & 31;
#pragma unroll
        for (int u = 0; u < 8; u++) {
            int c = oc0 + (u << 5);
            if (c < WF) {
                op[c] = (s0[c] + s0[c+1] + s1[c] + s1[c+1]) * (1.f / (COUT * 4));
            }
        }
    }
}

extern "C" void kernel_launch(void* const* d_in, const int* in_sizes, int n_in,
                              void* d_out, int out_size, void* d_ws, size_t ws_size,
                              hipStream_t stream) {
    const float* x     = (const float*)d_in[0];
    const float* w     = (const float*)d_in[1];
    const float* bias  = (const float*)d_in[2];
    const float* gamma = (const float*)d_in[3];
    const float* beta  = (const float*)d_in[4];
    float* out = (float*)d_out;

    float* part = (float*)d_ws;          // STB*32 floats of per-block partials
    float* acc  = part + STB * 32;       // 32 floats: s[16], q[16]

    k_stats<<<STB, 256, 0, stream>>>(x, w, bias, part);
    k_reduce<<<1, 256, 0, stream>>>(part, acc);
    k_csum<<<B * RBLKS, 256, 0, stream>>>(x, w, bias, gamma, beta, acc, out);
}

// Round 8
// 146.873 us; speedup vs baseline: 4.7301x; 1.0542x over previous
//
#include <hip/hip_runtime.h>

#define B     64
#define CIN   3
#define COUT  16
#define H     256
#define W     256
#define HW    (H*W)
#define CHW   (CIN*H*W)
#define HO    255            // conv out spatial
#define WO    255
#define HF    254            // window out spatial
#define WF    254
#define NPIXF 4161600.0f     // B*HO*WO
#define BN_EPS 1e-5f
#define C2TANH 2.8853900817779268f   // 2*log2(e)

#define SEGS  32                     // 8-px segments per conv row
#define NITEM (B * HO * SEGS)        // 522,240 = 2040 * 256
#define STB   (NITEM / 256)          // 2040 blocks, one segment per thread
#define RCHUNK (STB / 8)             // 255 partial entries per reduce-thread

#define RB    7                      // output rows per fused block (8 s-rows)
#define RBLKS 37                     // ceil(HF/RB)
#define LSTR  260                    // LDS s-tile row stride

typedef float f2 __attribute__((ext_vector_type(2)));

__device__ __forceinline__ float4 ld4(const float* p) { return *(const float4*)p; }
__device__ __forceinline__ f2 pkfma(f2 a, f2 b, f2 c) { return __builtin_elementwise_fma(a, b, c); }
__device__ __forceinline__ f2 spl(float v) { return (f2){v, v}; }

// Load the patch as (u, u+4) pixel-pairs: per (row, ic) the 5 pairs
//   P[j] = (x_j, x_{j+4}), j=0..4   built from two float4 loads + 1 scalar.
// off8 clamps the 9th column in-bounds for the tail segment (masked/unused).
__device__ __forceinline__ void load_patch_pk(const float* xp, int off8,
                                              f2 X0[CIN][5], f2 X1[CIN][5]) {
#pragma unroll
    for (int ic = 0; ic < CIN; ic++) {
        const float* p0 = xp + ic * HW;
        const float* p1 = p0 + W;
        float4 a = ld4(p0), b = ld4(p0 + 4);
        float  e = p0[off8];
        X0[ic][0] = (f2){a.x, b.x}; X0[ic][1] = (f2){a.y, b.y};
        X0[ic][2] = (f2){a.z, b.z}; X0[ic][3] = (f2){a.w, b.w};
        X0[ic][4] = (f2){b.x, e};
        float4 c4 = ld4(p1), d = ld4(p1 + 4);
        float  e1 = p1[off8];
        X1[ic][0] = (f2){c4.x, d.x}; X1[ic][1] = (f2){c4.y, d.y};
        X1[ic][2] = (f2){c4.z, d.z}; X1[ic][3] = (f2){c4.w, d.w};
        X1[ic][4] = (f2){d.x, e1};
    }
}

// 12 packed FMAs: conv for pixel pair (k, k+4) of channel c (weight pairs wq[0..11])
#define CONV_PK(f, k)                                              \
    f = pkfma(wq[0],  X0[0][k],   f);                              \
    f = pkfma(wq[1],  X0[0][k+1], f);                              \
    f = pkfma(wq[2],  X1[0][k],   f);                              \
    f = pkfma(wq[3],  X1[0][k+1], f);                              \
    f = pkfma(wq[4],  X0[1][k],   f);                              \
    f = pkfma(wq[5],  X0[1][k+1], f);                              \
    f = pkfma(wq[6],  X1[1][k],   f);                              \
    f = pkfma(wq[7],  X1[1][k+1], f);                              \
    f = pkfma(wq[8],  X0[2][k],   f);                              \
    f = pkfma(wq[9],  X0[2][k+1], f);                              \
    f = pkfma(wq[10], X1[2][k],   f);                              \
    f = pkfma(wq[11], X1[2][k+1], f);

// wpk layout per channel (32 floats): [0..23] w[j] duplicated at (2j,2j+1),
// [24,25]=bias dup, [26,27]=scale2 dup, [28,29]=shift2 dup, [30,31]=0.
// Each of 256 threads writes 2 consecutive slots.
template <bool WITH_BN>
__device__ __forceinline__ void load_wpk_pk(float* wpk, const float* w,
                                            const float* bias, const float* gamma,
                                            const float* beta, const float* acc,
                                            int tid) {
    int c  = tid >> 4;
    int k2 = (tid & 15) << 1;
    float sc2 = 0.f, sh2 = 0.f;
    if (WITH_BN && k2 >= 24) {
        float sv = acc[c], qv = acc[COUT + c];
        float mu  = sv * (1.f / NPIXF);
        float var = qv * (1.f / NPIXF) - mu * mu;
        float s   = gamma[c] * rsqrtf(var + BN_EPS);
        sc2 = s * C2TANH;
        sh2 = (beta[c] - mu * s) * C2TANH;
    }
#pragma unroll
    for (int t = 0; t < 2; t++) {
        int j = k2 + t;
        float v = 0.f;
        if (j < 24)       v = w[c * 12 + (j >> 1)];
        else if (j < 26)  v = bias[c];
        else if (j < 28)  v = sc2;
        else if (j < 30)  v = sh2;
        wpk[(c << 5) + j] = v;
    }
}

// ---- kernel 1: per-channel sum/sumsq of conv+bias; one 8-px segment per thread.
//      Packed-f32 conv; LDS transpose reduce; per-block partials (no atomics).
__global__ __launch_bounds__(256) void k_stats(const float* __restrict__ x,
                                               const float* __restrict__ w,
                                               const float* __restrict__ bias,
                                               float* __restrict__ part) {
    __shared__ float wpk[COUT * 32];
    __shared__ float tr[256 * 33];   // [thread][c] stride 33 -> bank (tid+c)%32
    __shared__ float red2[8 * 33];
    int tid = threadIdx.x;
    load_wpk_pk<false>(wpk, w, bias, nullptr, nullptr, nullptr, tid);
    __syncthreads();

    int item = blockIdx.x * 256 + tid;
    int jseg = item & (SEGS - 1);
    int row  = item >> 5;                 // b*HO + i
    int bb   = row / HO;
    int i    = row - bb * HO;
    const float* xp = x + (size_t)bb * CHW + i * W + (jseg << 3);
    bool tail = (jseg == SEGS - 1);
    int  off8 = tail ? 7 : 8;
    f2 mask3 = (f2){1.f, tail ? 0.f : 1.f};   // pixel 7 = pair3.y

    f2 X0[CIN][5], X1[CIN][5];
    load_patch_pk(xp, off8, X0, X1);

#pragma unroll
    for (int c = 0; c < COUT; c++) {
        const f2* wq = (const f2*)(wpk + (c << 5));   // wave-uniform -> broadcast
        f2 bp = wq[12];
        f2 sacc = spl(0.f), qacc = spl(0.f);
#pragma unroll
        for (int k = 0; k < 4; k++) {
            f2 f = bp;
            CONV_PK(f, k)
            if (k == 3) f *= mask3;
            sacc += f;
            qacc = pkfma(f, f, qacc);
        }
        tr[tid * 33 + c]        = sacc.x + sacc.y;
        tr[tid * 33 + COUT + c] = qacc.x + qacc.y;
    }
    __syncthreads();

    // column-chunk sums: thread (col=tid&31, chunk=tid>>5) sums 32 rows
    {
        int col = tid & 31, chunk = tid >> 5;
        int r0 = chunk << 5;
        float a0 = 0.f, a1 = 0.f, a2 = 0.f, a3 = 0.f;
#pragma unroll
        for (int k = 0; k < 32; k += 4) {
            a0 += tr[(r0 + k)     * 33 + col];
            a1 += tr[(r0 + k + 1) * 33 + col];
            a2 += tr[(r0 + k + 2) * 33 + col];
            a3 += tr[(r0 + k + 3) * 33 + col];
        }
        red2[chunk * 33 + col] = (a0 + a1) + (a2 + a3);
    }
    __syncthreads();
    if (tid < 32) {
        float s = 0.f;
#pragma unroll
        for (int k = 0; k < 8; k++) s += red2[k * 33 + tid];
        part[blockIdx.x * 32 + tid] = s;
    }
}

// ---- kernel 1b: fold 2040 x 32 partials -> acc[32] (one block, coalesced) ----
__global__ __launch_bounds__(256) void k_reduce(const float* __restrict__ part,
                                                float* __restrict__ acc) {
    __shared__ float red2[8 * 33];
    int tid = threadIdx.x;
    int col = tid & 31, chunk = tid >> 5;
    int base = chunk * RCHUNK;
    float a0 = 0.f, a1 = 0.f, a2 = 0.f, a3 = 0.f;
    int k = 0;
    for (; k + 3 < RCHUNK; k += 4) {
        a0 += part[(base + k)     * 32 + col];
        a1 += part[(base + k + 1) * 32 + col];
        a2 += part[(base + k + 2) * 32 + col];
        a3 += part[(base + k + 3) * 32 + col];
    }
    for (; k < RCHUNK; k++) a0 += part[(base + k) * 32 + col];
    red2[chunk * 33 + col] = (a0 + a1) + (a2 + a3);
    __syncthreads();
    if (tid < 32) {
        float s = 0.f;
#pragma unroll
        for (int j = 0; j < 8; j++) s += red2[j * 33 + tid];
        acc[tid] = s;
    }
}

// ---- kernel 2 (fused): BN finalize + s=sum_c tanh(relu(bn(conv))) tile + 2x2 window mean ----
__global__ __launch_bounds__(256) void k_csum(const float* __restrict__ x,
                                              const float* __restrict__ w,
                                              const float* __restrict__ bias,
                                              const float* __restrict__ gamma,
                                              const float* __restrict__ beta,
                                              const float* __restrict__ acc,
                                              float* __restrict__ out) {
    __shared__ float wpk[COUT * 32];
    __shared__ float sld[(RB + 1) * LSTR];
    int tid = threadIdx.x;
    load_wpk_pk<true>(wpk, w, bias, gamma, beta, acc, tid);
    int blk   = blockIdx.x;
    int bb    = blk / RBLKS;
    int rblk  = blk - bb * RBLKS;
    int rbase = rblk * RB;
    __syncthreads();

    // phase 1: one 8-pixel s-segment per thread (8 rows x 32 segs = 256 tasks)
    int sr = tid >> 5;               // 0..7
    int si = rbase + sr;
    int jseg = tid & 31;
    int j0 = jseg << 3;
    if (si < HO) {
        const float* xp = x + (size_t)bb * CHW + si * W + j0;
        int off8 = (jseg == 31) ? 7 : 8;
        f2 X0[CIN][5], X1[CIN][5];
        load_patch_pk(xp, off8, X0, X1);

        f2 racc[4];
#pragma unroll
        for (int k = 0; k < 4; k++) racc[k] = spl(0.f);

#pragma unroll
        for (int c = 0; c < COUT; c++) {
            const f2* wq = (const f2*)(wpk + (c << 5));   // uniform -> broadcast
            f2 bp = wq[12], s2 = wq[13], h2 = wq[14];
#pragma unroll
            for (int k = 0; k < 4; k++) {
                f2 f = bp;
                CONV_PK(f, k)
                f2 a2 = pkfma(s2, f, h2);                  // 2log2e*(scale*f+shift)
                a2 = __builtin_elementwise_max(a2, spl(0.f));  // relu (scaled)
                f2 E;
                E.x = __builtin_amdgcn_exp2f(a2.x);        // e^{2a}
                E.y = __builtin_amdgcn_exp2f(a2.y);
                E += spl(1.f);
                f2 r;
                r.x = __builtin_amdgcn_rcpf(E.x);
                r.y = __builtin_amdgcn_rcpf(E.y);
                racc[k] += r;                              // sum of 1/(e^{2a}+1)
            }
        }
        // s = COUT - 2*sum(r); pair k holds pixels (k, k+4)
        f2 sa[4];
#pragma unroll
        for (int k = 0; k < 4; k++) sa[k] = pkfma(spl(-2.f), racc[k], spl((float)COUT));
        float* sp = &sld[sr * LSTR + j0];
        *(float4*)sp       = make_float4(sa[0].x, sa[1].x, sa[2].x, sa[3].x);
        *(float4*)(sp + 4) = make_float4(sa[0].y, sa[1].y, sa[2].y, sa[3].y);
    }
    __syncthreads();

    // phase 2: 2x2 window means; thread -> (row tid>>5, cols (tid&31)+32u) coalesced
    int orl = tid >> 5;              // 0..7, valid rows 0..RB-1
    int orow = rbase + orl;
    if (orl < RB && orow < HF) {
        const float* s0 = &sld[orl * LSTR];
        const float* s1 = s0 + LSTR;
        float* op = out + ((size_t)bb * HF + orow) * WF;
        int oc0 = tid & 31;
#pragma unroll
        for (int u = 0; u < 8; u++) {
            int c = oc0 + (u << 5);
            if (c < WF) {
                op[c] = (s0[c] + s0[c+1] + s1[c] + s1[c+1]) * (1.f / (COUT * 4));
            }
        }
    }
}

extern "C" void kernel_launch(void* const* d_in, const int* in_sizes, int n_in,
                              void* d_out, int out_size, void* d_ws, size_t ws_size,
                              hipStream_t stream) {
    const float* x     = (const float*)d_in[0];
    const float* w     = (const float*)d_in[1];
    const float* bias  = (const float*)d_in[2];
    const float* gamma = (const float*)d_in[3];
    const float* beta  = (const float*)d_in[4];
    float* out = (float*)d_out;

    float* part = (float*)d_ws;          // STB*32 floats of per-block partials
    float* acc  = part + STB * 32;       // 32 floats: s[16], q[16]

    k_stats<<<STB, 256, 0, stream>>>(x, w, bias, part);
    k_reduce<<<1, 256, 0, stream>>>(part, acc);
    k_csum<<<B * RBLKS, 256, 0, stream>>>(x, w, bias, gamma, beta, acc, out);
}